// Round 9
// baseline (561.771 us; speedup 1.0000x reference)
//
#include <hip/hip_runtime.h>
#include <hip/hip_bf16.h>
#include <math.h>

#define RR 64
#define CC 32
#define NPTS (4*262144)

typedef __attribute__((ext_vector_type(8))) short short8;
typedef __attribute__((ext_vector_type(4))) float f32x4;
typedef __attribute__((ext_vector_type(4))) unsigned int u32x4;

static __device__ inline ushort f2bf(float x) {
    return __builtin_bit_cast(ushort, __float2bfloat16(x));
}
static __device__ inline uint32_t pk2(float a, float b) {
    return (uint32_t)f2bf(a) | ((uint32_t)f2bf(b) << 16);
}
static __device__ inline float relu(float x) { return fmaxf(x, 0.0f); }

// ws layout (floats unless noted):
//   float  Pcl[393216]   @ 0         channel-last fp32 planes [p][y][x][ch]
//   ushort W1T[24576]    @ 393216    layer1 A-frag table [nt<16][p<3][lane][e]
//   ushort W2T[16384]    follows     layer2 A-frag table [nt2<8][kt2<4][lane][e]
//   float  BC[256]       @ 413696    bias concat db1|rb1
// W1T+W2T = 81920 B staged to LDS; 2 blocks/CU = exactly the 160 KiB pool.

__global__ void prepass(const float* __restrict__ planes,
                        const float* __restrict__ dW1, const float* __restrict__ rW1,
                        const float* __restrict__ dW2,
                        const float* __restrict__ db1, const float* __restrict__ rb1,
                        float* __restrict__ ws) {
    int tid = blockIdx.x * blockDim.x + threadIdx.x;
    ushort* W1T = (ushort*)(ws + 393216);
    ushort* W2T = W1T + 24576;
    float*  BC  = ws + 413696;

    if (tid < 3 * CC * RR * RR) {
        int x = tid % RR, y = (tid / RR) % RR, ch = (tid / (RR * RR)) % CC, p = tid / (CC * RR * RR);
        ws[((p * RR + y) * RR + x) * CC + ch] = planes[tid];
    }
    if (tid < 24576) {   // W1T: tid = ((nt*3+p)*64 + l)*8 + e
        int e = tid & 7, l = (tid >> 3) & 63, rem = tid >> 9;
        int p = rem % 3, nt = rem / 3;
        int j = nt * 16 + (l & 15);
        int k = p * 32 + (l >> 4) * 8 + e;
        float v = (j < 128) ? dW1[j * 96 + k] : rW1[(j - 128) * 96 + k];
        W1T[tid] = f2bf(v);
    }
    if (tid < 16384) {   // W2T: tid = ((nt2*4+kt2)*64 + l)*8 + e
        int e = tid & 7, l = (tid >> 3) & 63, rem = tid >> 9;
        int kt2 = rem & 3, nt2 = rem >> 2;
        int j2 = nt2 * 16 + (l & 15);
        int k = kt2 * 32 + (l >> 4) * 8 + e;
        W2T[tid] = f2bf(dW2[j2 * 128 + k]);
    }
    if (tid < 256) BC[tid] = (tid < 128) ? db1[tid] : rb1[tid - 128];
}

// Bilinear-sample 8 channels (8g..8g+7) of one plane at (cx,cy), packed as a
// bf16 MFMA B-fragment. Pure named scalars -> registers.
static __device__ inline short8 sample_frag(const float* __restrict__ P,
                                            int plane_base, float cx, float cy, int g8) {
    float ix = (cx + 1.0f) * 31.5f; ix = fminf(fmaxf(ix, 0.0f), 63.0f);
    float iy = (cy + 1.0f) * 31.5f; iy = fminf(fmaxf(iy, 0.0f), 63.0f);
    int x0 = (int)ix, y0 = (int)iy;
    int x1 = min(x0 + 1, 63), y1 = min(y0 + 1, 63);
    float wx = ix - (float)x0, wy = iy - (float)y0;
    float w00 = (1.0f - wx) * (1.0f - wy), w01 = wx * (1.0f - wy);
    float w10 = (1.0f - wx) * wy,          w11 = wx * wy;
    int b00 = plane_base + (y0 * 64 + x0) * 32 + g8;
    int b01 = plane_base + (y0 * 64 + x1) * 32 + g8;
    int b10 = plane_base + (y1 * 64 + x0) * 32 + g8;
    int b11 = plane_base + (y1 * 64 + x1) * 32 + g8;
    f32x4 a0 = *(const f32x4*)(P + b00), a1 = *(const f32x4*)(P + b00 + 4);
    f32x4 c0 = *(const f32x4*)(P + b01), c1 = *(const f32x4*)(P + b01 + 4);
    f32x4 d0 = *(const f32x4*)(P + b10), d1 = *(const f32x4*)(P + b10 + 4);
    f32x4 e0 = *(const f32x4*)(P + b11), e1 = *(const f32x4*)(P + b11 + 4);
    float f0 = w00 * a0[0] + w01 * c0[0] + w10 * d0[0] + w11 * e0[0];
    float f1 = w00 * a0[1] + w01 * c0[1] + w10 * d0[1] + w11 * e0[1];
    float f2 = w00 * a0[2] + w01 * c0[2] + w10 * d0[2] + w11 * e0[2];
    float f3 = w00 * a0[3] + w01 * c0[3] + w10 * d0[3] + w11 * e0[3];
    float f4 = w00 * a1[0] + w01 * c1[0] + w10 * d1[0] + w11 * e1[0];
    float f5 = w00 * a1[1] + w01 * c1[1] + w10 * d1[1] + w11 * e1[1];
    float f6 = w00 * a1[2] + w01 * c1[2] + w10 * d1[2] + w11 * e1[2];
    float f7 = w00 * a1[3] + w01 * c1[3] + w10 * d1[3] + w11 * e1[3];
    u32x4 uu;
    uu[0] = pk2(f0, f1); uu[1] = pk2(f2, f3);
    uu[2] = pk2(f4, f5); uu[3] = pk2(f6, f7);
    return __builtin_bit_cast(short8, uu);
}

// rgb-head A-fragment for this lane (row = c = rgb channel for c<3, else 0).
static __device__ inline short8 rw_frag(const float* __restrict__ rW2,
                                        int kt2, int cc, int g8) {
    if (cc < 3) {
        const float* p = rW2 + cc * 128 + kt2 * 32 + g8;
        f32x4 v0 = *(const f32x4*)(p);
        f32x4 v1 = *(const f32x4*)(p + 4);
        u32x4 uu;
        uu[0] = pk2(v0[0], v0[1]); uu[1] = pk2(v0[2], v0[3]);
        uu[2] = pk2(v1[0], v1[1]); uu[3] = pk2(v1[2], v1[3]);
        return __builtin_bit_cast(short8, uu);
    }
    u32x4 z = {0u, 0u, 0u, 0u};
    return __builtin_bit_cast(short8, z);
}

#define MFMA(a, b, c) __builtin_amdgcn_mfma_f32_16x16x32_bf16((a), (b), (c), 0, 0, 0)

// One layer-1 output tile (j = 16*nt + 4g + r) for the 16-point tile:
// 3 MFMAs, bias+relu, pack into two bf16-pair u32s.
#define L1NT(nt, oA0, oA1) { \
    const ushort* wp_ = W1L + (nt) * 1536 + lane * 8; \
    short8 a0_ = *(const short8*)(wp_); \
    short8 a1_ = *(const short8*)(wp_ + 512); \
    short8 a2_ = *(const short8*)(wp_ + 1024); \
    f32x4 accA_ = {0.f,0.f,0.f,0.f}; \
    accA_ = MFMA(a0_, bfA0, accA_); \
    accA_ = MFMA(a1_, bfA1, accA_); \
    accA_ = MFMA(a2_, bfA2, accA_); \
    f32x4 bb_ = *(const f32x4*)(BCg + (nt) * 16 + 4 * g); \
    oA0 = pk2(relu(accA_[0] + bb_[0]), relu(accA_[1] + bb_[1])); \
    oA1 = pk2(relu(accA_[2] + bb_[2]), relu(accA_[3] + bb_[3])); }

// In-wave transpose: C-layout packed pairs (from nt = 2kt2, 2kt2+1) -> layer-2
// B-fragment for this kt2. Exchange among lanes {c, c+16, c+32, c+48}.
#define TRKT(p0a, p0b, p1a, p1b, outf) { \
    unsigned lo0_ = __shfl(p0a, s0, 64), hi0_ = __shfl(p1a, s0, 64); \
    unsigned lo1_ = __shfl(p0b, s0, 64), hi1_ = __shfl(p1b, s0, 64); \
    unsigned lo2_ = __shfl(p0a, s1, 64), hi2_ = __shfl(p1a, s1, 64); \
    unsigned lo3_ = __shfl(p0b, s1, 64), hi3_ = __shfl(p1b, s1, 64); \
    u32x4 uu_; \
    uu_[0] = gh ? hi0_ : lo0_;  uu_[1] = gh ? hi1_ : lo1_; \
    uu_[2] = gh ? hi2_ : lo2_;  uu_[3] = gh ? hi3_ : lo3_; \
    outf = __builtin_bit_cast(short8, uu_); }

// NOTE: second __launch_bounds__ arg behaves as min BLOCKS per CU on this
// toolchain: (512,4) forced a 64-VGPR cap -> GB-scale spill (R6/R7).
// (512,2) -> 128-VGPR cap; per-wave state sized (16-pt tiles) to fit it.
__global__ __launch_bounds__(512, 2)
void nerf_mfma(const float* __restrict__ points, const float* __restrict__ ws,
               const float* __restrict__ db2g, const float* __restrict__ dW3g,
               const float* __restrict__ db3g,
               const float* __restrict__ rW2g, const float* __restrict__ rb2g,
               float* __restrict__ rgb_out, float* __restrict__ den_out) {
    // LDS = weight tables only: 81920 B -> exactly 2 blocks per 160 KiB CU pool.
    __shared__ __align__(16) ushort SB[40960];

    const float* P   = ws;
    const float* BCg = ws + 413696;
    int tid = threadIdx.x;

    // stage weight tables to LDS (81920 B = 5120 x 16B)
    {
        const u32x4* src = (const u32x4*)(ws + 393216);
        u32x4* dst = (u32x4*)SB;
        for (int j = tid; j < 5120; j += 512) dst[j] = src[j];
    }
    __syncthreads();

    const ushort* W1L = SB;             // 24576 ushorts
    const ushort* W2L = SB + 24576;     // 16384 ushorts

    int wid = tid >> 6, lane = tid & 63;
    int c = lane & 15, g = lane >> 4;
    int g8 = 8 * g;
    int s0 = c + ((g & 1) << 5);        // transpose source lanes
    int s1 = s0 + 16;
    bool gh = (g >= 2);
    int gw = blockIdx.x * 8 + wid;      // 16384 waves, 4 tiles each, 16 pts/tile

    // hoisted per-kernel constants
    float b3  = db3g[0];
    float rb0 = rb2g[0], rb1v = rb2g[1], rb2v = rb2g[2];
    short8 rw0 = rw_frag(rW2g, 0, c, g8);
    short8 rw1 = rw_frag(rW2g, 1, c, g8);
    short8 rw2 = rw_frag(rW2g, 2, c, g8);
    short8 rw3 = rw_frag(rW2g, 3, c, g8);

    for (int it = 0; it < 4; ++it) {
        int pbase = (gw * 4 + it) * 16;

        // ---- features: lane (c,g) -> channels 8g..8g+7 of point c ----
        int ptA = pbase + c;
        float xa = points[ptA * 3 + 0], ya = points[ptA * 3 + 1], za = points[ptA * 3 + 2];
        short8 bfA0 = sample_frag(P, 0,      xa, ya, g8);
        short8 bfA1 = sample_frag(P, 131072, xa, za, g8);
        short8 bfA2 = sample_frag(P, 262144, ya, za, g8);

        unsigned pA0, pA1, qA0, qA1;

        // ---- rgb half (nt = 8..15): layer1 -> transpose -> head MFMA ----
        f32x4 rAacc = {0.f,0.f,0.f,0.f};
        #define RKT(kt2, rwv) { \
            L1NT(8 + 2*(kt2), pA0, pA1); \
            L1NT(9 + 2*(kt2), qA0, qA1); \
            short8 brA_; \
            TRKT(pA0, pA1, qA0, qA1, brA_); \
            rAacc = MFMA(rwv, brA_, rAacc); }
        RKT(0, rw0) RKT(1, rw1) RKT(2, rw2) RKT(3, rw3)
        #undef RKT

        // rgb store now (D[row=4g+r][col=c]; rows 0..2 live on g==0)
        if (g == 0) {
            rgb_out[ptA * 3 + 0] = 1.0f / (1.0f + expf(-(rAacc[0] + rb0)));
            rgb_out[ptA * 3 + 1] = 1.0f / (1.0f + expf(-(rAacc[1] + rb1v)));
            rgb_out[ptA * 3 + 2] = 1.0f / (1.0f + expf(-(rAacc[2] + rb2v)));
        }

        // ---- density half (nt = 0..7): layer1 -> transpose -> b2 frags ----
        short8 b2A0, b2A1, b2A2, b2A3;
        #define DKT(kt2, B2A) { \
            L1NT(2*(kt2),     pA0, pA1); \
            L1NT(2*(kt2) + 1, qA0, qA1); \
            TRKT(pA0, pA1, qA0, qA1, B2A); }
        DKT(0, b2A0) DKT(1, b2A1) DKT(2, b2A2) DKT(3, b2A3)
        #undef DKT

        // ---- layer2 + density fold (biases/weights from L1-resident global) ----
        float daccA = 0.f;
        #pragma unroll 2
        for (int nt2 = 0; nt2 < 8; ++nt2) {
            const ushort* wp = W2L + nt2 * 2048 + lane * 8;
            short8 a0 = *(const short8*)(wp);
            short8 a1 = *(const short8*)(wp + 512);
            short8 a2 = *(const short8*)(wp + 1024);
            short8 a3 = *(const short8*)(wp + 1536);
            f32x4 accA = {0.f,0.f,0.f,0.f};
            accA = MFMA(a0, b2A0, accA);
            accA = MFMA(a1, b2A1, accA);
            accA = MFMA(a2, b2A2, accA);
            accA = MFMA(a3, b2A3, accA);
            f32x4 bb = *(const f32x4*)(db2g + nt2 * 16 + 4 * g);
            f32x4 w3 = *(const f32x4*)(dW3g + nt2 * 16 + 4 * g);
            #pragma unroll
            for (int r = 0; r < 4; ++r)
                daccA = fmaf(w3[r], relu(accA[r] + bb[r]), daccA);
        }

        // ---- density head ----
        {
            float v = daccA; v += __shfl_xor(v, 16, 64); v += __shfl_xor(v, 32, 64); v += b3;
            float sp = fmaxf(v, 0.0f) + log1pf(expf(-fabsf(v)));
            if (g == 0) den_out[ptA] = sp;
        }
    }
}

extern "C" void kernel_launch(void* const* d_in, const int* in_sizes, int n_in,
                              void* d_out, int out_size, void* d_ws, size_t ws_size,
                              hipStream_t stream) {
    const float* points = (const float*)d_in[0];
    const float* planes = (const float*)d_in[1];
    const float* dW1    = (const float*)d_in[2];
    const float* db1    = (const float*)d_in[3];
    const float* dW2    = (const float*)d_in[4];
    const float* db2    = (const float*)d_in[5];
    const float* dW3    = (const float*)d_in[6];
    const float* db3    = (const float*)d_in[7];
    const float* rW1    = (const float*)d_in[8];
    const float* rb1    = (const float*)d_in[9];
    const float* rW2    = (const float*)d_in[10];
    const float* rb2    = (const float*)d_in[11];

    float* out     = (float*)d_out;
    float* rgb_out = out;                 // 3*NPTS floats
    float* den_out = out + 3 * NPTS;      // NPTS floats
    float* ws      = (float*)d_ws;

    prepass<<<1536, 256, 0, stream>>>(planes, dW1, rW1, dW2, db1, rb1, ws);
    nerf_mfma<<<2048, 512, 0, stream>>>(points, ws, db2, dW3, db3, rW2, rb2,
                                        rgb_out, den_out);
}

// Round 10
// 224.029 us; speedup vs baseline: 2.5076x; 2.5076x over previous
//
#include <hip/hip_runtime.h>
#include <hip/hip_bf16.h>
#include <math.h>

#define RR 64
#define CC 32
#define NPTS (4*262144)

typedef __attribute__((ext_vector_type(8))) short short8;
typedef __attribute__((ext_vector_type(4))) float f32x4;
typedef __attribute__((ext_vector_type(4))) unsigned int u32x4;

static __device__ inline ushort f2bf(float x) {
    return __builtin_bit_cast(ushort, __float2bfloat16(x));
}
static __device__ inline uint32_t pk2(float a, float b) {
    return (uint32_t)f2bf(a) | ((uint32_t)f2bf(b) << 16);
}
static __device__ inline float relu(float x) { return fmaxf(x, 0.0f); }

// ws layout:
//   float  Pcl[3*64*64*32]   @ 0          channel-last fp32 planes [p][y][x][ch]
//   ushort W1T[24576]        @ 393216 f   layer1 A-frag table [nt][p][lane][e]
//   ushort W2T[16384]        follows      layer2 A-frag table [nt2][kt2][lane][e]
//   float  CWS[896]          follows      BC[256]=db1|rb1 | db2[128] | dW3[128] | rW2[384]
// W1T..CWS = 85504 B, staged to LDS once per block (R5-proven layout).

__global__ void prepass(const float* __restrict__ planes,
                        const float* __restrict__ dW1, const float* __restrict__ rW1,
                        const float* __restrict__ dW2,
                        const float* __restrict__ db1, const float* __restrict__ rb1,
                        const float* __restrict__ db2, const float* __restrict__ dW3,
                        const float* __restrict__ rW2,
                        float* __restrict__ ws) {
    int tid = blockIdx.x * blockDim.x + threadIdx.x;
    ushort* W1T = (ushort*)(ws + 393216);
    ushort* W2T = W1T + 24576;
    float*  CWS = ws + 393216 + 20480;

    if (tid < 3 * CC * RR * RR) {
        int x = tid % RR, y = (tid / RR) % RR, ch = (tid / (RR * RR)) % CC, p = tid / (CC * RR * RR);
        ws[((p * RR + y) * RR + x) * CC + ch] = planes[tid];
    }
    if (tid < 24576) {   // W1T: tid = ((nt*3+p)*64 + l)*8 + e
        int e = tid & 7, l = (tid >> 3) & 63, rem = tid >> 9;
        int p = rem % 3, nt = rem / 3;
        int j = nt * 16 + (l & 15);
        int k = p * 32 + (l >> 4) * 8 + e;
        float v = (j < 128) ? dW1[j * 96 + k] : rW1[(j - 128) * 96 + k];
        W1T[tid] = f2bf(v);
    }
    if (tid < 16384) {   // W2T: tid = ((nt2*4+kt2)*64 + l)*8 + e
        int e = tid & 7, l = (tid >> 3) & 63, rem = tid >> 9;
        int kt2 = rem & 3, nt2 = rem >> 2;
        int j2 = nt2 * 16 + (l & 15);
        int k = kt2 * 32 + (l >> 4) * 8 + e;
        W2T[tid] = f2bf(dW2[j2 * 128 + k]);
    }
    if (tid < 256) CWS[tid]       = (tid < 128) ? db1[tid] : rb1[tid - 128];
    if (tid < 128) CWS[256 + tid] = db2[tid];
    if (tid < 128) CWS[384 + tid] = dW3[tid];
    if (tid < 384) CWS[512 + tid] = rW2[tid];
}

// Bilinear-sample 8 channels (8g..8g+7) of one plane at (cx,cy), packed as a
// bf16 MFMA B-fragment. Pure named scalars -> registers.
static __device__ inline short8 sample_frag(const float* __restrict__ P,
                                            int plane_base, float cx, float cy, int g8) {
    float ix = (cx + 1.0f) * 31.5f; ix = fminf(fmaxf(ix, 0.0f), 63.0f);
    float iy = (cy + 1.0f) * 31.5f; iy = fminf(fmaxf(iy, 0.0f), 63.0f);
    int x0 = (int)ix, y0 = (int)iy;
    int x1 = min(x0 + 1, 63), y1 = min(y0 + 1, 63);
    float wx = ix - (float)x0, wy = iy - (float)y0;
    float w00 = (1.0f - wx) * (1.0f - wy), w01 = wx * (1.0f - wy);
    float w10 = (1.0f - wx) * wy,          w11 = wx * wy;
    int b00 = plane_base + (y0 * 64 + x0) * 32 + g8;
    int b01 = plane_base + (y0 * 64 + x1) * 32 + g8;
    int b10 = plane_base + (y1 * 64 + x0) * 32 + g8;
    int b11 = plane_base + (y1 * 64 + x1) * 32 + g8;
    f32x4 a0 = *(const f32x4*)(P + b00), a1 = *(const f32x4*)(P + b00 + 4);
    f32x4 c0 = *(const f32x4*)(P + b01), c1 = *(const f32x4*)(P + b01 + 4);
    f32x4 d0 = *(const f32x4*)(P + b10), d1 = *(const f32x4*)(P + b10 + 4);
    f32x4 e0 = *(const f32x4*)(P + b11), e1 = *(const f32x4*)(P + b11 + 4);
    float f0 = w00 * a0[0] + w01 * c0[0] + w10 * d0[0] + w11 * e0[0];
    float f1 = w00 * a0[1] + w01 * c0[1] + w10 * d0[1] + w11 * e0[1];
    float f2 = w00 * a0[2] + w01 * c0[2] + w10 * d0[2] + w11 * e0[2];
    float f3 = w00 * a0[3] + w01 * c0[3] + w10 * d0[3] + w11 * e0[3];
    float f4 = w00 * a1[0] + w01 * c1[0] + w10 * d1[0] + w11 * e1[0];
    float f5 = w00 * a1[1] + w01 * c1[1] + w10 * d1[1] + w11 * e1[1];
    float f6 = w00 * a1[2] + w01 * c1[2] + w10 * d1[2] + w11 * e1[2];
    float f7 = w00 * a1[3] + w01 * c1[3] + w10 * d1[3] + w11 * e1[3];
    u32x4 uu;
    uu[0] = pk2(f0, f1); uu[1] = pk2(f2, f3);
    uu[2] = pk2(f4, f5); uu[3] = pk2(f6, f7);
    return __builtin_bit_cast(short8, uu);
}

#define MFMA(a, b, c) __builtin_amdgcn_mfma_f32_16x16x32_bf16((a), (b), (c), 0, 0, 0)

// NOTE: second __launch_bounds__ arg behaves as min BLOCKS per CU on this
// toolchain. (1024,1): 16 waves/CU = 4 waves/SIMD -> 128-VGPR cap; kernel
// live set ~70 (R5's was 88 incl. the deleted B-half) -> no spill expected.
__global__ __launch_bounds__(1024, 1)
void nerf_mfma(const float* __restrict__ points, const float* __restrict__ ws,
               const float* __restrict__ db3g, const float* __restrict__ rb2g,
               float* __restrict__ rgb_out, float* __restrict__ den_out) {
    // LDS: weights+consts 85504 B + per-wave H 16*16*136*2 = 69632 B -> 155136 B
    __shared__ __align__(16) ushort SB[42752];
    __shared__ __align__(16) ushort Hs[16][16][136];

    const float* P = ws;
    int tid = threadIdx.x;

    // ---- stage weight tables + consts into LDS (once per block) ----
    {
        const u32x4* src = (const u32x4*)(ws + 393216);
        u32x4* dst = (u32x4*)SB;
        for (int j = tid; j < 5344; j += 1024) dst[j] = src[j];
    }
    __syncthreads();

    const ushort* W1L = SB;                          // 24576 ushorts
    const ushort* W2L = SB + 24576;                  // 16384 ushorts
    const float*  Cl  = (const float*)(SB + 40960);  // BC | db2 | dW3 | rW2

    int wid = tid >> 6, lane = tid & 63;
    int c = lane & 15, g = lane >> 4;
    int g8 = 8 * g;
    ushort (*H)[136] = Hs[wid];
    int gw = blockIdx.x * 16 + wid;     // 16384 waves, 4 tiles each, 16 pts/tile

    float b3  = db3g[0];
    float rb0 = rb2g[0], rb1v = rb2g[1], rb2v = rb2g[2];

    for (int it = 0; it < 4; ++it) {
        int pbase = (gw * 4 + it) * 16;

        // ---- features: lane (c,g) -> channels 8g..8g+7 of point c ----
        int ptA = pbase + c;
        float xa = points[ptA * 3 + 0], ya = points[ptA * 3 + 1], za = points[ptA * 3 + 2];
        short8 bfA0 = sample_frag(P, 0,      xa, ya, g8);
        short8 bfA1 = sample_frag(P, 131072, xa, za, g8);
        short8 bfA2 = sample_frag(P, 262144, ya, za, g8);

        // ---- layer1, density half (j=0..127): -> H in LDS ----
        #pragma unroll 4
        for (int nt = 0; nt < 8; ++nt) {
            const ushort* wp = W1L + nt * 1536 + lane * 8;
            short8 a0 = *(const short8*)(wp);
            short8 a1 = *(const short8*)(wp + 512);
            short8 a2 = *(const short8*)(wp + 1024);
            f32x4 accA = {0.f,0.f,0.f,0.f};
            accA = MFMA(a0, bfA0, accA);
            accA = MFMA(a1, bfA1, accA);
            accA = MFMA(a2, bfA2, accA);
            f32x4 bb = *(const f32x4*)(Cl + nt * 16 + 4 * g);
            uint2 wA;
            wA.x = pk2(relu(accA[0] + bb[0]), relu(accA[1] + bb[1]));
            wA.y = pk2(relu(accA[2] + bb[2]), relu(accA[3] + bb[3]));
            *(uint2*)(&H[c][16 * nt + 4 * g]) = wA;
        }

        // ---- layer1, rgb half (j=128..255): fold rW2 immediately (VALU) ----
        float racc0A = 0.f, racc1A = 0.f, racc2A = 0.f;
        #pragma unroll 4
        for (int nt = 8; nt < 16; ++nt) {
            const ushort* wp = W1L + nt * 1536 + lane * 8;
            short8 a0 = *(const short8*)(wp);
            short8 a1 = *(const short8*)(wp + 512);
            short8 a2 = *(const short8*)(wp + 1024);
            f32x4 accA = {0.f,0.f,0.f,0.f};
            accA = MFMA(a0, bfA0, accA);
            accA = MFMA(a1, bfA1, accA);
            accA = MFMA(a2, bfA2, accA);
            int jo = (nt - 8) * 16 + 4 * g;
            f32x4 bb = *(const f32x4*)(Cl + 128 + jo);
            f32x4 w0 = *(const f32x4*)(Cl + 512 + jo);
            f32x4 w1 = *(const f32x4*)(Cl + 640 + jo);
            f32x4 w2 = *(const f32x4*)(Cl + 768 + jo);
            #pragma unroll
            for (int r = 0; r < 4; ++r) {
                float vA = relu(accA[r] + bb[r]);
                racc0A = fmaf(w0[r], vA, racc0A);
                racc1A = fmaf(w1[r], vA, racc1A);
                racc2A = fmaf(w2[r], vA, racc2A);
            }
        }

        // all lanes' H writes visible before cross-lane fragment reads (same wave)
        asm volatile("s_waitcnt lgkmcnt(0)" ::: "memory");
        __builtin_amdgcn_sched_barrier(0);

        // ---- layer2 B-frags: lane (c,g) reads h[k=32kt2+8g+e][pt] = H[pt][...] ----
        short8 b2A0 = *(const short8*)(&H[c][g8]);
        short8 b2A1 = *(const short8*)(&H[c][32 + g8]);
        short8 b2A2 = *(const short8*)(&H[c][64 + g8]);
        short8 b2A3 = *(const short8*)(&H[c][96 + g8]);

        // ---- layer2 + density fold ----
        float daccA = 0.f;
        #pragma unroll 2
        for (int nt2 = 0; nt2 < 8; ++nt2) {
            const ushort* wp = W2L + nt2 * 2048 + lane * 8;
            short8 a0 = *(const short8*)(wp);
            short8 a1 = *(const short8*)(wp + 512);
            short8 a2 = *(const short8*)(wp + 1024);
            short8 a3 = *(const short8*)(wp + 1536);
            f32x4 accA = {0.f,0.f,0.f,0.f};
            accA = MFMA(a0, b2A0, accA);
            accA = MFMA(a1, b2A1, accA);
            accA = MFMA(a2, b2A2, accA);
            accA = MFMA(a3, b2A3, accA);
            f32x4 bb = *(const f32x4*)(Cl + 256 + nt2 * 16 + 4 * g);
            f32x4 w3 = *(const f32x4*)(Cl + 384 + nt2 * 16 + 4 * g);
            #pragma unroll
            for (int r = 0; r < 4; ++r)
                daccA = fmaf(w3[r], relu(accA[r] + bb[r]), daccA);
        }

        // ---- heads: reduce over g via shfl, then store ----
        {
            float v = daccA; v += __shfl_xor(v, 16, 64); v += __shfl_xor(v, 32, 64); v += b3;
            float sp = fmaxf(v, 0.0f) + log1pf(expf(-fabsf(v)));
            if (g == 0) den_out[ptA] = sp;
        }
        {
            float v = racc0A; v += __shfl_xor(v, 16, 64); v += __shfl_xor(v, 32, 64); v += rb0;
            if (g == 0) rgb_out[ptA * 3 + 0] = 1.0f / (1.0f + expf(-v));
        }
        {
            float v = racc1A; v += __shfl_xor(v, 16, 64); v += __shfl_xor(v, 32, 64); v += rb1v;
            if (g == 0) rgb_out[ptA * 3 + 1] = 1.0f / (1.0f + expf(-v));
        }
        {
            float v = racc2A; v += __shfl_xor(v, 16, 64); v += __shfl_xor(v, 32, 64); v += rb2v;
            if (g == 0) rgb_out[ptA * 3 + 2] = 1.0f / (1.0f + expf(-v));
        }

        asm volatile("" ::: "memory");   // keep next tile's LDS writes after this tile's reads
    }
}

extern "C" void kernel_launch(void* const* d_in, const int* in_sizes, int n_in,
                              void* d_out, int out_size, void* d_ws, size_t ws_size,
                              hipStream_t stream) {
    const float* points = (const float*)d_in[0];
    const float* planes = (const float*)d_in[1];
    const float* dW1    = (const float*)d_in[2];
    const float* db1    = (const float*)d_in[3];
    const float* dW2    = (const float*)d_in[4];
    const float* db2    = (const float*)d_in[5];
    const float* dW3    = (const float*)d_in[6];
    const float* db3    = (const float*)d_in[7];
    const float* rW1    = (const float*)d_in[8];
    const float* rb1    = (const float*)d_in[9];
    const float* rW2    = (const float*)d_in[10];
    const float* rb2    = (const float*)d_in[11];

    float* out     = (float*)d_out;
    float* rgb_out = out;                 // 3*NPTS floats
    float* den_out = out + 3 * NPTS;      // NPTS floats
    float* ws      = (float*)d_ws;

    prepass<<<1536, 256, 0, stream>>>(planes, dW1, rW1, dW2, db1, rb1,
                                      db2, dW3, rW2, ws);
    nerf_mfma<<<1024, 1024, 0, stream>>>(points, ws, db3, rb2, rgb_out, den_out);
}